// Round 2
// baseline (16624.670 us; speedup 1.0000x reference)
//
#include <hip/hip_runtime.h>
#include <cstdint>
#include <cstddef>

typedef unsigned short u16;
typedef unsigned int u32;
typedef __attribute__((ext_vector_type(8))) short short8;
typedef __attribute__((ext_vector_type(4))) float f32x4;

#define AGENT_SCOPE __HIP_MEMORY_SCOPE_AGENT
#define SPIN_CAP 20000000
#define SMEM_BYTES 152584

__device__ __forceinline__ u16 f2bf(float f) {
  u32 u = __float_as_uint(f);
  return (u16)((u + 0x7FFFu + ((u >> 16) & 1u)) >> 16);
}
__device__ __forceinline__ float bf2f(u16 s) { return __uint_as_float(((u32)s) << 16); }
__device__ __forceinline__ float sigm(float x) { return 1.f / (1.f + __expf(-x)); }
__device__ __forceinline__ float tanha(float x) { return 1.f - 2.f / (__expf(2.f * x) + 1.f); }

__device__ __forceinline__ uint4 pack8(const float* p) {
  uint4 v;
  v.x = (u32)f2bf(p[0]) | ((u32)f2bf(p[1]) << 16);
  v.y = (u32)f2bf(p[2]) | ((u32)f2bf(p[3]) << 16);
  v.z = (u32)f2bf(p[4]) | ((u32)f2bf(p[5]) << 16);
  v.w = (u32)f2bf(p[6]) | ((u32)f2bf(p[7]) << 16);
  return v;
}

// Persistent LSTM autoencoder. Grid 256 WGs x 256 thr; col = bid&3 (16 batch),
// rowg = bid>>2 (8 hidden units -> 32 gate rows). LDS ~149KB -> 1 WG/CU, all
// blocks co-resident -> flag barriers safe.
// Ring layout: [par][col][rowg=64][b=16][u=8] bf16 -> producer stores 256B
// contiguous; consumer loads lane-contiguous. Barrier: one fetch_add per WG on
// a per-column counter; tid0 polls the single line (no 64-line poll storm).
__global__ void __launch_bounds__(256, 1)
lstm_ae_kernel(const float* __restrict__ x,
    const float* __restrict__ eWih0, const float* __restrict__ eWhh0,
    const float* __restrict__ ebi0,  const float* __restrict__ ebh0,
    const float* __restrict__ eWih1, const float* __restrict__ eWhh1,
    const float* __restrict__ ebi1,  const float* __restrict__ ebh1,
    const float* __restrict__ dWhh0,
    const float* __restrict__ dbi0,  const float* __restrict__ dbh0,
    const float* __restrict__ dWih1, const float* __restrict__ dWhh1,
    const float* __restrict__ dbi1,  const float* __restrict__ dbh1,
    const float* __restrict__ tlW,   const float* __restrict__ tlb,
    const float* __restrict__ lhW,   const float* __restrict__ lhb,
    const float* __restrict__ opW,   const float* __restrict__ opb,
    float* __restrict__ out, char* __restrict__ wsb)
{
  extern __shared__ char smem[];
  u16* sW0   = (u16*)(smem);              // enc: [32][648] cat(Wih0|Whh0); dec: [32][520] Whh0 + opW slice @u16 16640
  u16* sW1   = (u16*)(smem + 41472);      // [32][1032] cat(Wih1|Whh1)
  u16* sX    = (u16*)(smem + 107520);     // [16][136] x_t slice bf16
  u16* sH0   = (u16*)(smem + 111872);     // [16][520] staged h0
  u16* sH1   = (u16*)(smem + 128512);     // [16][520] staged h1
  float* sP  = (float*)(smem + 145152);   // 6 x [16][16] MFMA partial slots
  float* sBias = (float*)(smem + 151296); // [2][32]
  float* sC  = (float*)(smem + 151552);   // [2][16][8] cell state fp32
  float* sOPB= (float*)(smem + 152576);   // [2]

  #define SPV(slot,mm,nn) sP[(slot)*256 + (mm)*16 + (nn)]

  u32* colcnt = (u32*)wsb;                // 4 counters, 256B apart
  u32* gcnt  = (u32*)(wsb + 4096);
  float* zbuf= (float*)(wsb + 8192);      // [64][64]
  u16* h0r   = (u16*)(wsb + 32768);       // [2][4][64][16][8] bf16
  u16* h1r   = (u16*)(wsb + 163840);      // [2][4][64][16][8] bf16
  u32* h0ru  = (u32*)h0r;
  u32* h1ru  = (u32*)h1r;
  u32* outu  = (u32*)out;

  const int tid  = threadIdx.x;
  const int col  = blockIdx.x & 3;
  const int rowg = blockIdx.x >> 2;
  const int wid  = tid >> 6;
  const int lane = tid & 63;
  const int m    = lane & 15;
  const int qo   = (lane >> 4) * 8;

  u32 ep = 0;
  u32* mycnt = colcnt + col * 64;

  auto colbar = [&]() {
    ++ep;
    __syncthreads();   // drains all global stores (vmcnt0 before s_barrier)
    if (tid == 0) {
      __hip_atomic_fetch_add(mycnt, 1u, __ATOMIC_RELEASE, AGENT_SCOPE);
      const u32 tgt = ep * 64u;
      int it = 0;
      while (__hip_atomic_load(mycnt, __ATOMIC_RELAXED, AGENT_SCOPE) < tgt && ++it < SPIN_CAP) {}
      (void)__hip_atomic_load(mycnt, __ATOMIC_ACQUIRE, AGENT_SCOPE);  // L1/L2 invalidate
    }
    __syncthreads();
  };

  // stage one (par,col) ring image [64 rowg][16 b][8 u] -> sH [b][520]
  auto stage_ring = [&](u16* dst, const u16* src) {
    #pragma unroll
    for (int i = 0; i < 4; ++i) {
      int g = tid + 256 * i;           // lane-contiguous 16B groups
      int rg = g >> 4, b = g & 15;
      uint4 v = *(const uint4*)(src + g * 8);
      *(uint4*)(dst + b * 520 + rg * 8) = v;
    }
  };

  auto stage_xt = [&](int s) {
    int b = tid >> 4, seg = tid & 15;
    const float* p = x + (size_t)(col*16 + b)*131072 + (size_t)s*128 + seg*8;
    *(uint4*)(sX + b*136 + seg*8) = pack8(p);
  };

  // MFMA helper: one 16-row weight tile (row0) x A, accumulate over nkt k-tiles
  auto runs = [&](f32x4& acc, const u16* Wb, int wstr, int row0,
                  const u16* Ab, int astr, int nkt, int bk0, int ak0) {
    for (int i2 = 0; i2 < nkt; ++i2) {
      short8 a = *(const short8*)(Ab + m*astr + ak0 + i2*32 + qo);
      short8 b = *(const short8*)(Wb + (row0 + m)*wstr + bk0 + i2*32 + qo);
      acc = __builtin_amdgcn_mfma_f32_16x16x32_bf16(a, b, acc, 0, 0, 0);
    }
  };
  auto spstore = [&](int slot, const f32x4& a) {
    int mb = (lane >> 4) * 4;
    #pragma unroll
    for (int r = 0; r < 4; ++r) SPV(slot, mb + r, m) = a[r];
  };

  // gates: L0 i|f = slot0, g|o = slot1; L1 i|f = slot2+4, g|o = slot3+5
  auto act_store = [&](bool L0a, bool L1a, int p0, int p1) {
    int li = tid >> 7, b = (tid >> 3) & 15, u = tid & 7;
    bool act = li ? L1a : L0a;
    float hv = 0.f;
    if (act) {
      float gi, gf, gg, go;
      if (li == 0) {
        gi = SPV(0,b,u);   gf = SPV(0,b,8+u);
        gg = SPV(1,b,u);   go = SPV(1,b,8+u);
      } else {
        gi = SPV(2,b,u)   + SPV(4,b,u);
        gf = SPV(2,b,8+u) + SPV(4,b,8+u);
        gg = SPV(3,b,u)   + SPV(5,b,u);
        go = SPV(3,b,8+u) + SPV(5,b,8+u);
      }
      gi += sBias[li*32 + u];      gf += sBias[li*32 + 8 + u];
      gg += sBias[li*32 + 16 + u]; go += sBias[li*32 + 24 + u];
      float c = sC[(li*16 + b)*8 + u];
      c = sigm(gf)*c + sigm(gi)*tanha(gg);
      sC[(li*16 + b)*8 + u] = c;
      hv = sigm(go)*tanha(c);
    }
    u16 hb = f2bf(hv);
    u32 other = __shfl_xor((u32)hb, 1);
    if (act && !(u & 1)) {
      u32 v = (u32)hb | (other << 16);
      u32* ring = li ? h1ru : h0ru;
      int par = li ? p1 : p0;
      int idx = (((par*4 + col)*64 + rowg) << 6) + b*4 + (u >> 1);  // contiguous 256B/WG
      __hip_atomic_store(ring + idx, v, __ATOMIC_RELAXED, AGENT_SCOPE);
    }
  };

  // ================= P0: encoder weights (fp32 -> bf16 LDS) =================
  for (int i = tid; i < 32*80; i += 256) {      // W0cat [32][640]
    int n = i / 80, k = (i % 80) * 8;
    int g = ((n >> 3) << 9) + rowg*8 + (n & 7);
    const float* src = (k < 128) ? (eWih0 + g*128 + k) : (eWhh0 + g*512 + (k - 128));
    *(uint4*)(sW0 + n*648 + k) = pack8(src);
  }
  for (int i = tid; i < 32*128; i += 256) {     // W1cat [32][1024]
    int n = i >> 7, k = (i & 127) * 8;
    int g = ((n >> 3) << 9) + rowg*8 + (n & 7);
    const float* src = (k < 512) ? (eWih1 + g*512 + k) : (eWhh1 + g*512 + (k - 512));
    *(uint4*)(sW1 + n*1032 + k) = pack8(src);
  }
  if (tid < 64) {
    int li = tid >> 5, n = tid & 31;
    int g = ((n >> 3) << 9) + rowg*8 + (n & 7);
    sBias[li*32 + n] = li ? (ebi1[g] + ebh1[g]) : (ebi0[g] + ebh0[g]);
  }
  sC[tid] = 0.f;
  __syncthreads();

  // ================= P1: encoder scan (lag-1 pipelined, 1 barrier/slot) =====
  for (int s = 0; s <= 1024; ++s) {
    const bool L0 = (s < 1024);
    const bool L1 = (s >= 1);
    if (L0) stage_xt(s);
    stage_ring(sH0, h0r + ((((s-1)&1)*4) + col) * 8192);   // h0[s-1]
    stage_ring(sH1, h1r + ((((s-2)&1)*4) + col) * 8192);   // h1[s-2]
    __syncthreads();

    f32x4 accA = {0.f,0.f,0.f,0.f}, accB = {0.f,0.f,0.f,0.f};
    if (wid == 0) {
      if (L0) { runs(accA, sW0,648,0,  sX,136,4,0,0); runs(accA, sW0,648,0,  sH0,520,16,128,0); }
      if (L1) runs(accB, sW1,1032,0,  sH0,520,6,0,0);
    } else if (wid == 1) {
      if (L0) { runs(accA, sW0,648,16, sX,136,4,0,0); runs(accA, sW0,648,16, sH0,520,16,128,0); }
      if (L1) runs(accB, sW1,1032,16, sH0,520,6,0,0);
    } else if (wid == 2) {
      if (L1) { runs(accA, sW1,1032,0,  sH0,520,10,192,192); runs(accA, sW1,1032,0,  sH1,520,16,512,0); }
    } else {
      if (L1) { runs(accA, sW1,1032,16, sH0,520,10,192,192); runs(accA, sW1,1032,16, sH1,520,16,512,0); }
    }
    if (wid == 0)      { if (L0) spstore(0, accA); if (L1) spstore(2, accB); }
    else if (wid == 1) { if (L0) spstore(1, accA); if (L1) spstore(3, accB); }
    else if (wid == 2) { if (L1) spstore(4, accA); }
    else               { if (L1) spstore(5, accA); }
    __syncthreads();
    act_store(L0, L1, s & 1, (s-1) & 1);
    colbar();
  }

  // ================= P2: latent heads =================
  stage_ring(sH1, h1r + (4 + col) * 8192);   // h1[1023] (parity 1)
  __syncthreads();
  if (tid < 16) {     // z[b, rowg]
    int b = tid;
    float acc = tlb[rowg];
    for (int kk = 0; kk < 512; kk += 8) {
      short8 hv = *(const short8*)(sH1 + b*520 + kk);
      #pragma unroll
      for (int j = 0; j < 8; ++j) acc += bf2f((u16)hv[j]) * tlW[rowg*512 + kk + j];
    }
    int gb = col*16 + b;
    __hip_atomic_store(outu + 8388608 + gb*64 + rowg, __float_as_uint(acc), __ATOMIC_RELAXED, AGENT_SCOPE);
    __hip_atomic_store((u32*)zbuf + gb*64 + rowg, __float_as_uint(acc), __ATOMIC_RELAXED, AGENT_SCOPE);
  }
  __syncthreads();
  if (tid == 0) {     // global barrier (init_h mixes z across columns)
    __hip_atomic_fetch_add(gcnt, 1u, __ATOMIC_RELEASE, AGENT_SCOPE);
    int it = 0;
    while (__hip_atomic_load(gcnt, __ATOMIC_RELAXED, AGENT_SCOPE) < 256u && ++it < SPIN_CAP) {}
    (void)__hip_atomic_load(gcnt, __ATOMIC_ACQUIRE, AGENT_SCOPE);
  }
  __syncthreads();

  // ---- decoder weights ----
  for (int i = tid; i < 32*64; i += 256) {      // Whh0_dec [32][512]
    int n = i >> 6, k = (i & 63) * 8;
    int g = ((n >> 3) << 9) + rowg*8 + (n & 7);
    *(uint4*)(sW0 + n*520 + k) = pack8(dWhh0 + g*512 + k);
  }
  for (int i = tid; i < 32*128; i += 256) {     // W1cat dec
    int n = i >> 7, k = (i & 127) * 8;
    int g = ((n >> 3) << 9) + rowg*8 + (n & 7);
    const float* src = (k < 512) ? (dWih1 + g*512 + k) : (dWhh1 + g*512 + (k - 512));
    *(uint4*)(sW1 + n*1032 + k) = pack8(src);
  }
  for (int i = tid; i < 2*64; i += 256) {       // opW rows 2*rowg, 2*rowg+1
    int dd = i >> 6, k = (i & 63) * 8;
    *(uint4*)(sW0 + 16640 + dd*520 + k) = pack8(opW + (rowg*2 + dd)*512 + k);
  }
  if (tid < 64) {
    int li = tid >> 5, n = tid & 31;
    int g = ((n >> 3) << 9) + rowg*8 + (n & 7);
    sBias[li*32 + n] = li ? (dbi1[g] + dbh1[g]) : (dbi0[g] + dbh0[g]);
  }
  if (tid < 2) sOPB[tid] = opb[rowg*2 + tid];
  sC[tid] = 0.f;
  // init_h = tanh(z @ lhW^T + lhb), torch flat view -> (L,B,H):
  // init_h[l][bb][h] = M[l*32 + bb/2][(bb&1)*512 + h]
  {
    int li = tid >> 7, hh = (tid >> 4) & 7, qb = (tid >> 3) & 1, u = tid & 7;
    int r = li*32 + 8*col + hh;
    int c = qb*512 + rowg*8 + u;
    int bl = 2*hh + qb;
    float acc = lhb[c];
    for (int k = 0; k < 64; ++k) acc += zbuf[r*64 + k] * lhW[c*64 + k];
    u16 hb = f2bf(tanha(acc));
    u32 other = __shfl_xor((u32)hb, 1);
    if (!(u & 1)) {
      u32 v = (u32)hb | (other << 16);
      u32* ring = li ? h1ru : h0ru;
      int idx = (((4 + col)*64 + rowg) << 6) + bl*4 + (u >> 1);   // parity 1 = h[-1]
      __hip_atomic_store(ring + idx, v, __ATOMIC_RELAXED, AGENT_SCOPE);
    }
  }
  colbar();

  // ================= P3: decoder scan + fused recon ===========
  for (int s = 0; s <= 1025; ++s) {
    const bool L0 = (s < 1024);
    const bool L1 = (s >= 1 && s <= 1024);
    const bool RC = (s >= 2);
    stage_ring(sH0, h0r + ((((s-1)&1)*4) + col) * 8192);
    stage_ring(sH1, h1r + ((((s-2)&1)*4) + col) * 8192);
    __syncthreads();

    f32x4 accA = {0.f,0.f,0.f,0.f}, accB = {0.f,0.f,0.f,0.f};
    if (wid == 0) {
      if (L0) runs(accA, sW0,520,0,  sH0,520,16,0,0);
      if (L1) runs(accB, sW1,1032,0,  sH0,520,8,0,0);
    } else if (wid == 1) {
      if (L0) runs(accA, sW0,520,16, sH0,520,16,0,0);
      if (L1) runs(accB, sW1,1032,16, sH0,520,8,0,0);
    } else if (wid == 2) {
      if (L1) { runs(accA, sW1,1032,0,  sH0,520,8,256,256); runs(accA, sW1,1032,0,  sH1,520,16,512,0); }
    } else {
      if (L1) { runs(accA, sW1,1032,16, sH0,520,8,256,256); runs(accA, sW1,1032,16, sH1,520,16,512,0); }
    }
    if (wid == 0)      { if (L0) spstore(0, accA); if (L1) spstore(2, accB); }
    else if (wid == 1) { if (L0) spstore(1, accA); if (L1) spstore(3, accB); }
    else if (wid == 2) { if (L1) spstore(4, accA); }
    else               { if (L1) spstore(5, accA); }
    __syncthreads();
    act_store(L0, L1, s & 1, (s-1) & 1);

    if (RC) {   // recon[tau=s-2] = sigmoid(h1dec[tau] @ opW^T + opb)
      __syncthreads();
      int b = tid >> 4, dd = (tid >> 3) & 1, pt = tid & 7;
      float acc = 0.f;
      int k0 = pt * 64;
      for (int kk = 0; kk < 64; kk += 8) {
        short8 hv = *(const short8*)(sH1 + b*520 + k0 + kk);
        short8 wv = *(const short8*)(sW0 + 16640 + dd*520 + k0 + kk);
        #pragma unroll
        for (int j = 0; j < 8; ++j) acc += bf2f((u16)hv[j]) * bf2f((u16)wv[j]);
      }
      sP[tid] = acc;
      __syncthreads();
      if (tid < 32) {
        int b2 = tid >> 1, d2 = tid & 1;
        float sum = sOPB[d2];
        #pragma unroll
        for (int j = 0; j < 8; ++j) sum += sP[b2*16 + d2*8 + j];
        float rv = sigm(sum);
        size_t oidx = (size_t)(col*16 + b2)*131072 + (size_t)(s - 2)*128 + rowg*2 + d2;
        __hip_atomic_store(outu + oidx, __float_as_uint(rv), __ATOMIC_RELAXED, AGENT_SCOPE);
      }
    }
    if (s < 1025) colbar();
  }
  #undef SPV
}

extern "C" void kernel_launch(void* const* d_in, const int* in_sizes, int n_in,
                              void* d_out, int out_size, void* d_ws, size_t ws_size,
                              hipStream_t stream) {
  (void)in_sizes; (void)n_in; (void)out_size; (void)ws_size;
  hipFuncSetAttribute(reinterpret_cast<const void*>(lstm_ae_kernel),
                      hipFuncAttributeMaxDynamicSharedMemorySize, SMEM_BYTES);
  hipMemsetAsync(d_ws, 0, 294912, stream);   // counters + zbuf + rings (enc h[-1]=0)
  lstm_ae_kernel<<<dim3(256), dim3(256), SMEM_BYTES, stream>>>(
      (const float*)d_in[0],
      (const float*)d_in[1],  (const float*)d_in[2],
      (const float*)d_in[3],  (const float*)d_in[4],
      (const float*)d_in[5],  (const float*)d_in[6],
      (const float*)d_in[7],  (const float*)d_in[8],
      (const float*)d_in[10],
      (const float*)d_in[11], (const float*)d_in[12],
      (const float*)d_in[13], (const float*)d_in[14],
      (const float*)d_in[15], (const float*)d_in[16],
      (const float*)d_in[17], (const float*)d_in[18],
      (const float*)d_in[19], (const float*)d_in[20],
      (const float*)d_in[21], (const float*)d_in[22],
      (float*)d_out, (char*)d_ws);
}

// Round 4
// 6443.667 us; speedup vs baseline: 2.5800x; 2.5800x over previous
//
#include <hip/hip_runtime.h>
#include <cstdint>
#include <cstddef>

typedef unsigned short u16;
typedef unsigned int u32;
typedef __attribute__((ext_vector_type(8))) short short8;
typedef __attribute__((ext_vector_type(4))) float f32x4;

#define AGENT_SCOPE __HIP_MEMORY_SCOPE_AGENT
#define SPIN_CAP 20000000
#define POLL_CAP 200000
#define SENT 0xFFFFFFFFu

__device__ __forceinline__ u16 f2bf(float f) {
  u32 u = __float_as_uint(f);
  return (u16)((u + 0x7FFFu + ((u >> 16) & 1u)) >> 16);
}
__device__ __forceinline__ float bf2f(u16 s) { return __uint_as_float(((u32)s) << 16); }
__device__ __forceinline__ float sigm(float x) { return 1.f / (1.f + __expf(-x)); }
__device__ __forceinline__ float tanha(float x) { return 1.f - 2.f / (__expf(2.f * x) + 1.f); }
__device__ __forceinline__ void wait_vm0() { asm volatile("s_waitcnt vmcnt(0)" ::: "memory"); }

// Barrier-free persistent LSTM autoencoder.
// 256 WGs x 256 thr: col = bid&3 (16 batches), rowg = bid>>2 in [0,64) (8 hidden
// units = 32 gate rows). h exchange via depth-3 LLC ring, bf16 pairs packed in
// dwords; consumers poll the DATA dwords (agent relaxed loads, R1-verified to
// observe remote stores) until != SENT; producers SENT-clear the buffer reused
// at slot s+1 (safe: completing stage of h[s-1] implies all WGs staged h[s-2];
// the stage's vmcnt(0) orders clears before the next slot's data stores).
// No flags, no RMW, no acquire-invalidate on the hot path.
__global__ void __launch_bounds__(256, 1)
lstm_ae_kernel(const float* __restrict__ x,
    const float* __restrict__ eWih0, const float* __restrict__ eWhh0,
    const float* __restrict__ ebi0,  const float* __restrict__ ebh0,
    const float* __restrict__ eWih1, const float* __restrict__ eWhh1,
    const float* __restrict__ ebi1,  const float* __restrict__ ebh1,
    const float* __restrict__ dWhh0,
    const float* __restrict__ dbi0,  const float* __restrict__ dbh0,
    const float* __restrict__ dWih1, const float* __restrict__ dWhh1,
    const float* __restrict__ dbi1,  const float* __restrict__ dbh1,
    const float* __restrict__ tlW,   const float* __restrict__ tlb,
    const float* __restrict__ lhW,   const float* __restrict__ lhb,
    const float* __restrict__ opW,   const float* __restrict__ opb,
    float* __restrict__ out, char* __restrict__ wsb)
{
  __shared__ __align__(16) u16 sH0[16 * 520];   // staged h0 bf16, row stride 520
  __shared__ __align__(16) u16 sH1[16 * 520];
  __shared__ __align__(16) u16 sX[16 * 136];
  __shared__ __align__(16) u16 sOPW[2 * 520];
  __shared__ float sP[4 * 256];                  // per-wave MFMA partials [16b][16n]
  __shared__ float sBias[64];                    // [2 layer][32 gate-rows]
  __shared__ float sC[256];                      // [2][16 b][8 u] cell state fp32
  __shared__ float sZ[16 * 64];
  __shared__ float sOPB[4];

  u32* gcnt  = (u32*)wsb;
  float* zbuf= (float*)(wsb + 4096);             // [64][64]
  u32* h0r   = (u32*)(wsb + 32768);              // [3 q][4 col][64 rowg][64 dw]
  u32* h1r   = (u32*)(wsb + 229376);             // same (196608 B each)

  const int tid  = threadIdx.x;
  const int col  = blockIdx.x & 3;
  const int rowg = blockIdx.x >> 2;              // 0..63
  const int wid  = tid >> 6;
  const int lane = tid & 63;
  const int m    = lane & 15;
  const int qo   = (lane >> 4) * 8;

  // ---------- helpers ----------
  // poll+stage one slot's h0 (q0) and optionally h1 (q1) column images into LDS
  auto stage_slot = [&](int q0, int q1, bool p0on, bool p1on) {
    const u32* b0 = h0r + ((q0 * 4 + col) << 12) + tid;
    const u32* b1 = h1r + ((q1 * 4 + col) << 12) + tid;
    u32 v0[16], v1[16];
    int it = 0; bool ok = false;
    while (!ok && it++ < POLL_CAP) {
      ok = true;
      if (p0on) {
        #pragma unroll
        for (int i = 0; i < 16; ++i) {
          v0[i] = __hip_atomic_load(b0 + i * 256, __ATOMIC_RELAXED, AGENT_SCOPE);
          ok &= (v0[i] != SENT);
        }
      }
      if (p1on) {
        #pragma unroll
        for (int i = 0; i < 16; ++i) {
          v1[i] = __hip_atomic_load(b1 + i * 256, __ATOMIC_RELAXED, AGENT_SCOPE);
          ok &= (v1[i] != SENT);
        }
      }
    }
    u32* dH0 = (u32*)sH0; u32* dH1 = (u32*)sH1;
    #pragma unroll
    for (int i = 0; i < 16; ++i) {
      int g = i * 256 + tid;
      int rg = g >> 6, b = (g >> 2) & 15, udw = g & 3;
      if (p0on) dH0[b * 260 + rg * 4 + udw] = v0[i];
      if (p1on) dH1[b * 260 + rg * 4 + udw] = v1[i];
    }
  };

  // SENT-clear own blocks of the buffers reused at slot s+1 (issued during compute;
  // drained by the pre-act __syncthreads, i.e. before this slot's data stores land)
  auto clears = [&](int s) {
    if (tid < 64) {
      int cq0 = (s + 1) % 3, cq1 = s % 3;
      __hip_atomic_store(h0r + ((cq0 * 4 + col) << 12) + (rowg << 6) + tid,
                         SENT, __ATOMIC_RELAXED, AGENT_SCOPE);
      __hip_atomic_store(h1r + ((cq1 * 4 + col) << 12) + (rowg << 6) + tid,
                         SENT, __ATOMIC_RELAXED, AGENT_SCOPE);
    }
  };

  auto stage_xt = [&](int s) {
    int b = tid >> 4, seg = tid & 15;
    const float* p = x + (size_t)(col * 16 + b) * 131072 + (size_t)s * 128 + seg * 8;
    float4 f0 = *(const float4*)p, f1 = *(const float4*)(p + 4);
    uint4 v;
    v.x = (u32)f2bf(f0.x) | ((u32)f2bf(f0.y) << 16);
    v.y = (u32)f2bf(f0.z) | ((u32)f2bf(f0.w) << 16);
    v.z = (u32)f2bf(f1.x) | ((u32)f2bf(f1.y) << 16);
    v.w = (u32)f2bf(f1.z) | ((u32)f2bf(f1.w) << 16);
    *(uint4*)(sX + b * 136 + seg * 8) = v;
  };

  // B-fragment loader: weight row, bf16-converted, k window kofs+qo..+8
  auto ldw = [&](const float* W, int ld, int row, int kofs) -> short8 {
    const float* p = W + (size_t)row * ld + kofs + qo;
    float4 f0 = *(const float4*)p, f1 = *(const float4*)(p + 4);
    short8 r;
    r[0] = (short)f2bf(f0.x); r[1] = (short)f2bf(f0.y);
    r[2] = (short)f2bf(f0.z); r[3] = (short)f2bf(f0.w);
    r[4] = (short)f2bf(f1.x); r[5] = (short)f2bf(f1.y);
    r[6] = (short)f2bf(f1.z); r[7] = (short)f2bf(f1.w);
    return r;
  };

  // gates (R2-verified mapping): L0 slots 0,1; L1 slots 2,3.
  auto act_store = [&](bool L0a, bool L1a, int q0, int q1) {
    int li = tid >> 7, b = (tid >> 3) & 15, u = tid & 7;
    bool actv = li ? L1a : L0a;
    float hv = 0.f;
    if (actv) {
      float gi = sP[(li*2)*256   + b*16 + u]     + sBias[li*32 + u];
      float gf = sP[(li*2)*256   + b*16 + 8 + u] + sBias[li*32 + 8 + u];
      float gg = sP[(li*2+1)*256 + b*16 + u]     + sBias[li*32 + 16 + u];
      float go = sP[(li*2+1)*256 + b*16 + 8 + u] + sBias[li*32 + 24 + u];
      float c = sC[(li*16 + b)*8 + u];
      c = sigm(gf)*c + sigm(gi)*tanha(gg);
      sC[(li*16 + b)*8 + u] = c;
      hv = sigm(go)*tanha(c);
    }
    u16 hb = f2bf(hv);
    u32 other = __shfl_xor((u32)hb, 1);
    if (actv && !(u & 1)) {
      u32 v = (u32)hb | (other << 16);
      u32* ring = li ? h1r : h0r;
      int q = li ? q1 : q0;
      __hip_atomic_store(ring + ((q * 4 + col) << 12) + (rowg << 6) + b * 4 + (u >> 1),
                         v, __ATOMIC_RELAXED, AGENT_SCOPE);
    }
  };

  auto gbar = [&](u32 target) {
    __syncthreads();
    if (tid == 0) {
      __hip_atomic_fetch_add(gcnt, 1u, __ATOMIC_RELEASE, AGENT_SCOPE);
      int it = 0;
      while (__hip_atomic_load(gcnt, __ATOMIC_RELAXED, AGENT_SCOPE) < target && ++it < SPIN_CAP) {}
      (void)__hip_atomic_load(gcnt, __ATOMIC_ACQUIRE, AGENT_SCOPE);
    }
    __syncthreads();
  };

  // lane's weight row: n = (wid&1)*16 + m; gate = n>>3, unit = n&7
  const int nl = (wid & 1) * 16 + m;
  const int gw = ((nl >> 3) << 9) + rowg * 8 + (nl & 7);

  short8 wb[32];

  // ================= encoder weights -> VGPRs =================
  if (wid < 2) {
    #pragma unroll
    for (int t = 0; t < 4; ++t)  wb[t]      = ldw(eWih0, 128, gw, t * 32);
    #pragma unroll
    for (int t = 0; t < 16; ++t) wb[4 + t]  = ldw(eWhh0, 512, gw, t * 32);
  } else {
    #pragma unroll
    for (int t = 0; t < 16; ++t) wb[t]      = ldw(eWih1, 512, gw, t * 32);
    #pragma unroll
    for (int t = 0; t < 16; ++t) wb[16 + t] = ldw(eWhh1, 512, gw, t * 32);
  }
  if (tid < 64) {
    int li = tid >> 5, n = tid & 31;
    int g = ((n >> 3) << 9) + rowg * 8 + (n & 7);
    sBias[li * 32 + n] = li ? (ebi1[g] + ebh1[g]) : (ebi0[g] + ebh0[g]);
  }
  sC[tid] = 0.f;
  __syncthreads();

  // ================= encoder scan (lag-1 pipelined, barrier-free) =====
  for (int s = 0; s <= 1024; ++s) {
    const bool L0 = (s < 1024), L1 = (s >= 1);
    if (L0) stage_xt(s);
    stage_slot((s + 2) % 3, (s + 1) % 3, true, s >= 1);   // h0[s-1], h1[s-2]
    __syncthreads();
    clears(s);

    f32x4 acc = {0.f, 0.f, 0.f, 0.f};
    if (wid < 2) {
      if (L0) {
        #pragma unroll
        for (int t = 0; t < 4; ++t) {
          short8 a = *(const short8*)(sX + m * 136 + t * 32 + qo);
          acc = __builtin_amdgcn_mfma_f32_16x16x32_bf16(a, wb[t], acc, 0, 0, 0);
        }
        #pragma unroll
        for (int t = 0; t < 16; ++t) {
          short8 a = *(const short8*)(sH0 + m * 520 + t * 32 + qo);
          acc = __builtin_amdgcn_mfma_f32_16x16x32_bf16(a, wb[4 + t], acc, 0, 0, 0);
        }
      }
    } else {
      if (L1) {
        #pragma unroll
        for (int t = 0; t < 16; ++t) {
          short8 a = *(const short8*)(sH0 + m * 520 + t * 32 + qo);
          acc = __builtin_amdgcn_mfma_f32_16x16x32_bf16(a, wb[t], acc, 0, 0, 0);
        }
        #pragma unroll
        for (int t = 0; t < 16; ++t) {
          short8 a = *(const short8*)(sH1 + m * 520 + t * 32 + qo);
          acc = __builtin_amdgcn_mfma_f32_16x16x32_bf16(a, wb[16 + t], acc, 0, 0, 0);
        }
      }
    }
    {
      bool wact = (wid < 2) ? L0 : L1;
      if (wact) {
        int mb = (lane >> 4) * 4;
        #pragma unroll
        for (int r = 0; r < 4; ++r) sP[wid * 256 + (mb + r) * 16 + m] = acc[r];
      }
    }
    __syncthreads();                       // drains clears (vmcnt0) + SP visible
    act_store(L0, L1, s % 3, (s + 2) % 3); // h0[s] -> q s%3, h1[s-1] -> q (s-1)%3
  }

  // ================= latent: z = h1[1023] @ tlW^T + tlb ====================
  {  // h1[1023] is in h1 ring q0 (stored at slot 1024)
    const u32* b1 = h1r + ((0 * 4 + col) << 12) + tid;
    u32 v1[16];
    int it = 0; bool ok = false;
    while (!ok && it++ < POLL_CAP) {
      ok = true;
      #pragma unroll
      for (int i = 0; i < 16; ++i) {
        v1[i] = __hip_atomic_load(b1 + i * 256, __ATOMIC_RELAXED, AGENT_SCOPE);
        ok &= (v1[i] != SENT);
      }
    }
    u32* dH1 = (u32*)sH1;
    #pragma unroll
    for (int i = 0; i < 16; ++i) {
      int g = i * 256 + tid;
      dH1[((g >> 2) & 15) * 260 + (g >> 6) * 4 + (g & 3)] = v1[i];
    }
  }
  __syncthreads();
  if (tid < 16) {
    int b = tid;
    float acc = tlb[rowg];
    for (int kk = 0; kk < 512; kk += 8) {
      short8 hv = *(const short8*)(sH1 + b * 520 + kk);
      #pragma unroll
      for (int j = 0; j < 8; ++j) acc += bf2f((u16)hv[j]) * tlW[rowg * 512 + kk + j];
    }
    int gb = col * 16 + b;
    __hip_atomic_store((u32*)zbuf + gb * 64 + rowg, __float_as_uint(acc),
                       __ATOMIC_RELAXED, AGENT_SCOPE);
    out[8388608 + gb * 64 + rowg] = acc;
  }
  gbar(256);        // z visible everywhere; all WGs done with encoder rings

  // ---- reset rings for decoder: all q SENT (own blocks) ----
  if (tid < 64) {
    #pragma unroll
    for (int q = 0; q < 3; ++q) {
      __hip_atomic_store(h0r + ((q * 4 + col) << 12) + (rowg << 6) + tid,
                         SENT, __ATOMIC_RELAXED, AGENT_SCOPE);
      __hip_atomic_store(h1r + ((q * 4 + col) << 12) + (rowg << 6) + tid,
                         SENT, __ATOMIC_RELAXED, AGENT_SCOPE);
    }
  }
  wait_vm0();       // clears committed before init_h data stores below

  // ================= decoder weights -> VGPRs ==============================
  if (wid < 2) {
    #pragma unroll
    for (int t = 0; t < 16; ++t) wb[t] = ldw(dWhh0, 512, gw, t * 32);
  } else {
    #pragma unroll
    for (int t = 0; t < 16; ++t) wb[t]      = ldw(dWih1, 512, gw, t * 32);
    #pragma unroll
    for (int t = 0; t < 16; ++t) wb[16 + t] = ldw(dWhh1, 512, gw, t * 32);
  }
  if (tid < 64) {
    int li = tid >> 5, n = tid & 31;
    int g = ((n >> 3) << 9) + rowg * 8 + (n & 7);
    sBias[li * 32 + n] = li ? (dbi1[g] + dbh1[g]) : (dbi0[g] + dbh0[g]);
  }
  for (int i = tid; i < 2 * 64; i += 256) {      // opW rows rowg*2, rowg*2+1
    int dd = i >> 6, k = (i & 63) * 8;
    const float* p = opW + (size_t)(rowg * 2 + dd) * 512 + k;
    float4 f0 = *(const float4*)p, f1 = *(const float4*)(p + 4);
    uint4 v;
    v.x = (u32)f2bf(f0.x) | ((u32)f2bf(f0.y) << 16);
    v.y = (u32)f2bf(f0.z) | ((u32)f2bf(f0.w) << 16);
    v.z = (u32)f2bf(f1.x) | ((u32)f2bf(f1.y) << 16);
    v.w = (u32)f2bf(f1.z) | ((u32)f2bf(f1.w) << 16);
    *(uint4*)(sOPW + dd * 520 + k) = v;
  }
  if (tid < 2) sOPB[tid] = opb[rowg * 2 + tid];
  sC[tid] = 0.f;

  // ---- init_h = tanh(z @ lhW^T + lhb), torch flat view (L,B,H):
  // init_h[l][bb][h] = M[l*32 + bb/2][(bb&1)*512 + h]; store as h[-1] into q2.
  {
    int ri = tid >> 4, kk = (tid & 15) * 4;
    int zr = ((ri >> 3) << 5) + 8 * col + (ri & 7);
    #pragma unroll
    for (int j = 0; j < 4; ++j)
      sZ[ri * 64 + kk + j] = __uint_as_float(
          __hip_atomic_load((u32*)zbuf + zr * 64 + kk + j, __ATOMIC_RELAXED, AGENT_SCOPE));
  }
  __syncthreads();
  {
    int li = tid >> 7, hh = (tid >> 4) & 7, qb = (tid >> 3) & 1, u = tid & 7;
    int cc = qb * 512 + rowg * 8 + u;
    int bl = 2 * hh + qb;
    float acc2 = lhb[cc];
    const float* lw = lhW + (size_t)cc * 64;
    #pragma unroll 8
    for (int k = 0; k < 64; ++k) acc2 += sZ[(li * 8 + hh) * 64 + k] * lw[k];
    u16 hb = f2bf(tanha(acc2));
    u32 other = __shfl_xor((u32)hb, 1);
    if (!(u & 1)) {
      u32 v = (u32)hb | (other << 16);
      u32* ring = li ? h1r : h0r;
      __hip_atomic_store(ring + ((2 * 4 + col) << 12) + (rowg << 6) + bl * 4 + (u >> 1),
                         v, __ATOMIC_RELAXED, AGENT_SCOPE);
    }
  }
  gbar(512);        // ring resets globally visible before any decoder poll

  // ================= decoder scan + fused recon ============================
  for (int s = 0; s <= 1025; ++s) {
    const bool L0 = (s < 1024), L1 = (s >= 1 && s <= 1024), RC = (s >= 2);
    stage_slot((s + 2) % 3, (s + 1) % 3, s <= 1024, s >= 1);
    __syncthreads();
    clears(s);

    f32x4 acc = {0.f, 0.f, 0.f, 0.f};
    if (wid < 2) {
      if (L0) {
        #pragma unroll
        for (int t = 0; t < 16; ++t) {
          short8 a = *(const short8*)(sH0 + m * 520 + t * 32 + qo);
          acc = __builtin_amdgcn_mfma_f32_16x16x32_bf16(a, wb[t], acc, 0, 0, 0);
        }
      }
    } else {
      if (L1) {
        #pragma unroll
        for (int t = 0; t < 16; ++t) {
          short8 a = *(const short8*)(sH0 + m * 520 + t * 32 + qo);
          acc = __builtin_amdgcn_mfma_f32_16x16x32_bf16(a, wb[t], acc, 0, 0, 0);
        }
        #pragma unroll
        for (int t = 0; t < 16; ++t) {
          short8 a = *(const short8*)(sH1 + m * 520 + t * 32 + qo);
          acc = __builtin_amdgcn_mfma_f32_16x16x32_bf16(a, wb[16 + t], acc, 0, 0, 0);
        }
      }
    }
    {
      bool wact = (wid < 2) ? L0 : L1;
      if (wact) {
        int mb = (lane >> 4) * 4;
        #pragma unroll
        for (int r = 0; r < 4; ++r) sP[wid * 256 + (mb + r) * 16 + m] = acc[r];
      }
    }
    __syncthreads();
    act_store(L0, L1, s % 3, (s + 2) % 3);

    if (RC) {   // recon[t=s-2] = sigmoid(h1dec[s-2] @ opW^T + opb), d = rowg*2+{0,1}
      __syncthreads();
      int b = tid >> 4, dd = (tid >> 3) & 1, pt = tid & 7;
      float acc2 = 0.f;
      int k0 = pt * 64;
      for (int kk = 0; kk < 64; kk += 8) {
        short8 hv = *(const short8*)(sH1 + b * 520 + k0 + kk);
        short8 wv = *(const short8*)(sOPW + dd * 520 + k0 + kk);
        #pragma unroll
        for (int j = 0; j < 8; ++j) acc2 += bf2f((u16)hv[j]) * bf2f((u16)wv[j]);
      }
      sP[tid] = acc2;
      __syncthreads();
      if (tid < 32) {
        int b2 = tid >> 1, d2 = tid & 1;
        float sum = sOPB[d2];
        #pragma unroll
        for (int j = 0; j < 8; ++j) sum += sP[b2 * 16 + d2 * 8 + j];
        out[(size_t)(col * 16 + b2) * 131072 + (size_t)(s - 2) * 128 + rowg * 2 + d2]
            = sigm(sum);
      }
    }
  }
}

extern "C" void kernel_launch(void* const* d_in, const int* in_sizes, int n_in,
                              void* d_out, int out_size, void* d_ws, size_t ws_size,
                              hipStream_t stream) {
  (void)in_sizes; (void)n_in; (void)out_size; (void)ws_size;
  char* ws = (char*)d_ws;
  // control + zbuf
  hipMemsetAsync(ws, 0, 32768, stream);
  // h0 ring: q0,q1 = SENT (not yet produced), q2 = 0.0 data (h0[-1] = 0)
  hipMemsetAsync(ws + 32768, 0xFF, 131072, stream);
  hipMemsetAsync(ws + 163840, 0x00, 65536, stream);
  // h1 ring: q0,q1 = SENT, q2 = 0.0 data (h1[-1] = 0)
  hipMemsetAsync(ws + 229376, 0xFF, 131072, stream);
  hipMemsetAsync(ws + 360448, 0x00, 65536, stream);
  lstm_ae_kernel<<<dim3(256), dim3(256), 0, stream>>>(
      (const float*)d_in[0],
      (const float*)d_in[1],  (const float*)d_in[2],
      (const float*)d_in[3],  (const float*)d_in[4],
      (const float*)d_in[5],  (const float*)d_in[6],
      (const float*)d_in[7],  (const float*)d_in[8],
      (const float*)d_in[10],
      (const float*)d_in[11], (const float*)d_in[12],
      (const float*)d_in[13], (const float*)d_in[14],
      (const float*)d_in[15], (const float*)d_in[16],
      (const float*)d_in[17], (const float*)d_in[18],
      (const float*)d_in[19], (const float*)d_in[20],
      (const float*)d_in[21], (const float*)d_in[22],
      (float*)d_out, (char*)d_ws);
}